// Round 2
// baseline (237.454 us; speedup 1.0000x reference)
//
#include <hip/hip_runtime.h>

// Problem constants
#define B_  2
#define S_  2048
#define D_  1024
#define H_  16
#define DK_ 64

typedef __bf16 bf16;
typedef __bf16 bf16x8 __attribute__((ext_vector_type(8)));
typedef __bf16 bf16x4 __attribute__((ext_vector_type(4)));
typedef float  f32x4  __attribute__((ext_vector_type(4)));
typedef short  s16x4  __attribute__((ext_vector_type(4)));

#define GLD16(gptr, lptr) __builtin_amdgcn_global_load_lds( \
    (const __attribute__((address_space(1))) void*)(gptr),  \
    (__attribute__((address_space(3))) void*)(lptr), 16, 0, 0)

// Legacy K=16 bf16 MFMA: B-fragment layout (lane -> B[k=g*4+e][n=r]) matches
// the QK^T accumulator C-layout exactly -> P feeds PV with NO LDS round-trip.
#if __has_builtin(__builtin_amdgcn_mfma_f32_16x16x16bf16_1k)
static __device__ __forceinline__ f32x4 mfma16(bf16x4 a, bf16x4 b, f32x4 c) {
  return __builtin_amdgcn_mfma_f32_16x16x16bf16_1k(*(s16x4*)&a, *(s16x4*)&b, c, 0, 0, 0);
}
#else
static __device__ __forceinline__ f32x4 mfma16(bf16x4 a, bf16x4 b, f32x4 c) {
  asm("v_mfma_f32_16x16x16_bf16 %0, %1, %2, %0" : "+v"(c) : "v"(a), "v"(b));
  return c;
}
#endif

// ---------------------------------------------------------------------------
// fused fp32 -> bf16 cast for all 7 tensors in ONE launch (2048 elems/block)
// ---------------------------------------------------------------------------
__global__ __launch_bounds__(256) void cast_all(
    const float* __restrict__ q, const float* __restrict__ k, const float* __restrict__ v,
    const float* __restrict__ wq, const float* __restrict__ wk, const float* __restrict__ wv,
    const float* __restrict__ wo,
    bf16* __restrict__ qb, bf16* __restrict__ kb, bf16* __restrict__ vb,
    bf16* __restrict__ wqb, bf16* __restrict__ wkb, bf16* __restrict__ wvb,
    bf16* __restrict__ wob) {
  int blk = blockIdx.x;
  const float* in; bf16* out; int base;
  if      (blk < 2048) { in = q;  out = qb;  base = blk; }
  else if (blk < 4096) { in = k;  out = kb;  base = blk - 2048; }
  else if (blk < 6144) { in = v;  out = vb;  base = blk - 4096; }
  else if (blk < 6656) { in = wq; out = wqb; base = blk - 6144; }
  else if (blk < 7168) { in = wk; out = wkb; base = blk - 6656; }
  else if (blk < 7680) { in = wv; out = wvb; base = blk - 7168; }
  else                 { in = wo; out = wob; base = blk - 7680; }
  int i = (base * 256 + threadIdx.x) * 8;
  float4 a = *(const float4*)(in + i);
  float4 b = *(const float4*)(in + i + 4);
  bf16x8 o;
  o[0] = (bf16)a.x; o[1] = (bf16)a.y; o[2] = (bf16)a.z; o[3] = (bf16)a.w;
  o[4] = (bf16)b.x; o[5] = (bf16)b.y; o[6] = (bf16)b.z; o[7] = (bf16)b.w;
  *(bf16x8*)(out + i) = o;
}

// ---------------------------------------------------------------------------
// Fused Q/K/V projection. Tile 128x64, BK=64, 6 blocks/CU. grid (512,3).
// z=0: Qh = (q Wq^T + b)*sc2 (pre-scaled), head-split [B,H,S,64]
// z=1: Kh = k Wk^T + b, head-split;  z=2: Vt = Wv v^T + b(row), [D, B*S]
// ---------------------------------------------------------------------------
__global__ __launch_bounds__(256, 6) void gemm_qkv(
    const bf16* __restrict__ qb, const bf16* __restrict__ kb, const bf16* __restrict__ vb,
    const bf16* __restrict__ wq, const bf16* __restrict__ wk, const bf16* __restrict__ wv,
    const float* __restrict__ biq, const float* __restrict__ bik, const float* __restrict__ biv,
    bf16* __restrict__ Qh, bf16* __restrict__ Kh, bf16* __restrict__ Vt) {
  __shared__ bf16 As[128 * 64];   // 16 KB
  __shared__ bf16 Bs[64 * 64];    // 8 KB
  const int z = blockIdx.y;
  const bf16 *A, *Bm; const float* bias; bf16* Cout;
  int bx, by, N;
  if (z == 0)      { A = qb; Bm = wq; bias = biq; Cout = Qh; }
  else if (z == 1) { A = kb; Bm = wk; bias = bik; Cout = Kh; }
  else             { A = wv; Bm = vb; bias = biv; Cout = Vt; }
  if (z < 2) { by = blockIdx.x & 31; bx = blockIdx.x >> 5; N = D_; }
  else       { bx = blockIdx.x & 63; by = blockIdx.x >> 6; N = B_ * S_; }
  const int K = D_;

  const int tid  = threadIdx.x;
  const int wave = tid >> 6, lane = tid & 63;
  const int g = lane >> 4, r = lane & 15;
  const int m0 = by * 128, n0 = bx * 64;

  f32x4 acc[2][4] = {};
  const int srow = tid >> 3;  // 0..31
  const int sp   = tid & 7;   // 16B block in 128B row

  for (int k0 = 0; k0 < K; k0 += 64) {
    __syncthreads();
#pragma unroll
    for (int rep = 0; rep < 4; rep++) {       // A: 128 rows
      int row = rep * 32 + srow;
      int bb  = sp ^ (row & 7);
      GLD16(A + (size_t)(m0 + row) * K + k0 + bb * 8, As + rep * 2048 + wave * 512);
    }
#pragma unroll
    for (int rep = 0; rep < 2; rep++) {       // B: 64 rows
      int row = rep * 32 + srow;
      int bb  = sp ^ (row & 7);
      GLD16(Bm + (size_t)(n0 + row) * K + k0 + bb * 8, Bs + rep * 2048 + wave * 512);
    }
    __syncthreads();

#pragma unroll
    for (int kc = 0; kc < 2; kc++) {
      bf16x8 af[2], bfr[4];
#pragma unroll
      for (int i = 0; i < 2; i++) {
        int row = wave * 32 + i * 16 + r;
        af[i] = *(const bf16x8*)(As + row * 64 + (((kc * 4 + g) ^ (row & 7)) * 8));
      }
#pragma unroll
      for (int j = 0; j < 4; j++) {
        int row = j * 16 + r;
        bfr[j] = *(const bf16x8*)(Bs + row * 64 + (((kc * 4 + g) ^ (row & 7)) * 8));
      }
#pragma unroll
      for (int i = 0; i < 2; i++)
#pragma unroll
        for (int j = 0; j < 4; j++)
          acc[i][j] = __builtin_amdgcn_mfma_f32_16x16x32_bf16(af[i], bfr[j], acc[i][j], 0, 0, 0);
    }
  }

  const float qscale = 0.18033688f;  // (1/sqrt(64)) * log2(e), folded into Q
#pragma unroll
  for (int i = 0; i < 2; i++) {
#pragma unroll
    for (int j = 0; j < 4; j++) {
#pragma unroll
      for (int t = 0; t < 4; t++) {
        int mrow = m0 + wave * 32 + i * 16 + g * 4 + t;
        int col  = n0 + j * 16 + r;
        float val = acc[i][j][t];
        if (z < 2) {
          val += bias[col];
          if (z == 0) val *= qscale;
          int bb2 = mrow >> 11, s = mrow & (S_ - 1);
          int hh = col >> 6, d = col & 63;
          Cout[(((size_t)(bb2 * H_ + hh)) * S_ + s) * 64 + d] = (bf16)val;
        } else {
          val += bias[mrow];
          Cout[(size_t)mrow * N + col] = (bf16)val;
        }
      }
    }
  }
}

// ---------------------------------------------------------------------------
// Final projection: out = AO Wo^T + b (fp32). Tile 128x64, BK=64, 6 blocks/CU.
// ---------------------------------------------------------------------------
__global__ __launch_bounds__(256, 6) void gemm_out(const bf16* __restrict__ A,
                                                   const bf16* __restrict__ Bm,
                                                   const float* __restrict__ bias,
                                                   float* __restrict__ Cout) {
  __shared__ bf16 As[128 * 64];   // 16 KB
  __shared__ bf16 Bs[64 * 64];    // 8 KB
  const int K = D_, N = D_;
  const int tid  = threadIdx.x;
  const int wave = tid >> 6, lane = tid & 63;
  const int g = lane >> 4, r = lane & 15;
  const int bx = blockIdx.x & 15, by = blockIdx.x >> 4;
  const int m0 = by * 128, n0 = bx * 64;

  f32x4 acc[2][4] = {};
  const int srow = tid >> 3;
  const int sp   = tid & 7;

  for (int k0 = 0; k0 < K; k0 += 64) {
    __syncthreads();
#pragma unroll
    for (int rep = 0; rep < 4; rep++) {
      int row = rep * 32 + srow;
      int bb  = sp ^ (row & 7);
      GLD16(A + (size_t)(m0 + row) * K + k0 + bb * 8, As + rep * 2048 + wave * 512);
    }
#pragma unroll
    for (int rep = 0; rep < 2; rep++) {
      int row = rep * 32 + srow;
      int bb  = sp ^ (row & 7);
      GLD16(Bm + (size_t)(n0 + row) * K + k0 + bb * 8, Bs + rep * 2048 + wave * 512);
    }
    __syncthreads();

#pragma unroll
    for (int kc = 0; kc < 2; kc++) {
      bf16x8 af[2], bfr[4];
#pragma unroll
      for (int i = 0; i < 2; i++) {
        int row = wave * 32 + i * 16 + r;
        af[i] = *(const bf16x8*)(As + row * 64 + (((kc * 4 + g) ^ (row & 7)) * 8));
      }
#pragma unroll
      for (int j = 0; j < 4; j++) {
        int row = j * 16 + r;
        bfr[j] = *(const bf16x8*)(Bs + row * 64 + (((kc * 4 + g) ^ (row & 7)) * 8));
      }
#pragma unroll
      for (int i = 0; i < 2; i++)
#pragma unroll
        for (int j = 0; j < 4; j++)
          acc[i][j] = __builtin_amdgcn_mfma_f32_16x16x32_bf16(af[i], bfr[j], acc[i][j], 0, 0, 0);
    }
  }

#pragma unroll
  for (int i = 0; i < 2; i++)
#pragma unroll
    for (int j = 0; j < 4; j++)
#pragma unroll
      for (int t = 0; t < 4; t++) {
        int mrow = m0 + wave * 32 + i * 16 + g * 4 + t;
        int col  = n0 + j * 16 + r;
        Cout[(size_t)mrow * N + col] = acc[i][j][t] + bias[col];
      }
}

// ---------------------------------------------------------------------------
// Flash attention v3 — P stays in registers.
// r10 post-mortem: dbuf/vmcnt was neutral (MfmaUtil 25->25) => stall was NOT
// the staging drain. LDS-pipe arithmetic: Ps round-trip (write+lgkmcnt(0)
// drain+read, 8KB/wave/iter, the 3.1M bank conflicts) was ~1/3 of LDS traffic
// AND a serial dependency chain. Fix: PV now uses the legacy K=16
// v_mfma_f32_16x16x16_bf16 whose B-fragment layout (lane -> B[k=g*4+e][n=r])
// IS the QK^T accumulator layout (sacc lane(g,r) = S[key=g*4+t][q=r]) —
// P converts to bf16 in-register and feeds PV directly. V is read as
// ds_read_b64 fragments (A[m=d(r)][k=key g*4+e]). No Ps buffer, no lgkm
// drains, no Ps bank conflicts. LDS 38->32KB, still 4 blocks/CU (grid 1024
// = perfect residency).
// ---------------------------------------------------------------------------
__global__ __launch_bounds__(256, 4) void flash_attn(const bf16* __restrict__ Qh,
                                                     const bf16* __restrict__ Kh,
                                                     const bf16* __restrict__ Vt,
                                                     bf16* __restrict__ Apart,
                                                     float* __restrict__ Lpart) {
  __shared__ bf16 Ks[2][64 * 64];   // 16 KB (double-buffered)
  __shared__ bf16 Vs[2][64 * 64];   // 16 KB (double-buffered)

  const int tid  = threadIdx.x;
  const int wave = tid >> 6, lane = tid & 63;
  const int g = lane >> 4, r = lane & 15;

  int qt = blockIdx.x >> 6;          // 0..15
  int kh = blockIdx.x & 1;           // 0..1
  int bh = (blockIdx.x >> 1) & 31;   // 0..31
  int h = bh & (H_ - 1), b = bh >> 4;

  const bf16* Kbase = Kh + ((size_t)bh * S_ + kh * 1024) * DK_;
  const bf16* Vbase = Vt + (size_t)h * 64 * (B_ * S_) + (size_t)b * S_ + kh * 1024;

  bf16x8 bq[2][2];
#pragma unroll
  for (int sq = 0; sq < 2; sq++) {
    int qrow = qt * 128 + wave * 32 + sq * 16 + r;
    const bf16* qp = Qh + ((size_t)bh * S_ + qrow) * DK_;
#pragma unroll
    for (int kc = 0; kc < 2; kc++)
      bq[sq][kc] = *(const bf16x8*)(qp + kc * 32 + g * 8);
  }

  f32x4 acc_o[2][4] = {};
  float l_run[2] = {0.f, 0.f};

  const int srow = tid >> 3, spp = tid & 7;

  // 4 GLD16 per thread per stage (2 K + 2 V)
#define STAGE_KV(J, BUF) do {                                                        \
    _Pragma("unroll")                                                                \
    for (int rep = 0; rep < 2; rep++) {                                              \
      int rr = rep * 32 + srow;                                                      \
      int bb = spp ^ (rr & 7);                                                       \
      GLD16(Kbase + (size_t)((J) * 64 + rr) * 64 + bb * 8,                           \
            &Ks[BUF][rep * 2048 + wave * 512]);                                      \
      GLD16(Vbase + (size_t)rr * (B_ * S_) + (J) * 64 + bb * 8,                      \
            &Vs[BUF][rep * 2048 + wave * 512]);                                      \
    }                                                                                \
  } while (0)

  STAGE_KV(0, 0);   // prologue: tile 0 in flight

  for (int j0 = 0; j0 < 16; j0++) {
    const int buf = j0 & 1;
    __builtin_amdgcn_s_barrier();
    if (j0 < 15) {
      STAGE_KV(j0 + 1, buf ^ 1);
      asm volatile("s_waitcnt vmcnt(4)" ::: "memory");   // tile j0 drained; new 4 in flight
    } else {
      asm volatile("s_waitcnt vmcnt(0)" ::: "memory");
    }
    __builtin_amdgcn_s_barrier();

    const bf16* KsB = Ks[buf];
    const bf16* VsB = Vs[buf];

    // ---- QK^T: S[key][q] for 64 keys x 16 q (x2 sq) ----
    bf16x8 ak[4][2];
#pragma unroll
    for (int ks = 0; ks < 4; ks++) {
      int kr = ks * 16 + r;
#pragma unroll
      for (int kc = 0; kc < 2; kc++)
        ak[ks][kc] = *(const bf16x8*)(KsB + kr * 64 + (((kc * 4 + g) ^ (kr & 7)) * 8));
    }
    f32x4 sacc[2][4] = {};
    __builtin_amdgcn_s_setprio(1);
#pragma unroll
    for (int sq = 0; sq < 2; sq++)
#pragma unroll
      for (int ks = 0; ks < 4; ks++)
#pragma unroll
        for (int kc = 0; kc < 2; kc++)
          sacc[sq][ks] = __builtin_amdgcn_mfma_f32_16x16x32_bf16(ak[ks][kc], bq[sq][kc],
                                                                 sacc[sq][ks], 0, 0, 0);
    __builtin_amdgcn_s_setprio(0);

    // ---- exp -> in-register P fragment -> PV via K=16 MFMA ----
#pragma unroll
    for (int ks = 0; ks < 4; ks++) {
      bf16x4 pk[2];
#pragma unroll
      for (int sq = 0; sq < 2; sq++) {
        float rs = 0.f;
#pragma unroll
        for (int t = 0; t < 4; t++) {
          float pv = __builtin_amdgcn_exp2f(sacc[sq][ks][t]);
          rs += pv;
          pk[sq][t] = (bf16)pv;
        }
        l_run[sq] += rs;
      }
      __builtin_amdgcn_s_setprio(1);
#pragma unroll
      for (int dsub = 0; dsub < 4; dsub++) {
        int dr = dsub * 16 + r;
        // keys ks*16 + g*4 .. +3 : 16B-block cb = ks*2+(g>>1) (XOR-swizzled), half (g&1)
        bf16x4 av4 = *(const bf16x4*)(VsB + dr * 64 +
                                      (((ks * 2 + (g >> 1)) ^ (dr & 7)) * 8) + (g & 1) * 4);
#pragma unroll
        for (int sq = 0; sq < 2; sq++)
          acc_o[sq][dsub] = mfma16(av4, pk[sq], acc_o[sq][dsub]);
      }
      __builtin_amdgcn_s_setprio(0);
    }
  }
#undef STAGE_KV

#pragma unroll
  for (int sq = 0; sq < 2; sq++) {
    float l = l_run[sq];
    l += __shfl_xor(l, 16, 64);
    l += __shfl_xor(l, 32, 64);
    int s = qt * 128 + wave * 32 + sq * 16 + r;
    if (g == 0)
      Lpart[(size_t)kh * (B_ * H_ * S_) + (size_t)bh * S_ + s] = l;
    size_t base = (size_t)kh * (B_ * S_ * (size_t)D_) + ((size_t)b * S_ + s) * D_ + (size_t)h * 64;
#pragma unroll
    for (int dsub = 0; dsub < 4; dsub++) {
      bf16x4 o;
#pragma unroll
      for (int t = 0; t < 4; t++) o[t] = (bf16)(acc_o[sq][dsub][t]);
      *(bf16x4*)(Apart + base + dsub * 16 + g * 4) = o;
    }
  }
}

// ---------------------------------------------------------------------------
// combine: AO = (A0 + A1) / (l0 + l1). 8 elems/thread.
// ---------------------------------------------------------------------------
__global__ __launch_bounds__(256) void combine(const bf16* __restrict__ Apart,
                                               const float* __restrict__ Lpart,
                                               bf16* __restrict__ AO) {
  const size_t EQ = (size_t)B_ * S_ * D_;
  const int LHALF = B_ * H_ * S_;
  int idx = (blockIdx.x * 256 + threadIdx.x) * 8;
  int token = idx >> 10;           // b*S + s
  int dcol  = idx & (D_ - 1);
  int b = token >> 11, s = token & (S_ - 1);
  int h = dcol >> 6;
  int li = (b * H_ + h) * S_ + s;
  float inv = 1.0f / (Lpart[li] + Lpart[li + LHALF]);
  bf16x8 a0 = *(const bf16x8*)(Apart + idx);
  bf16x8 a1 = *(const bf16x8*)(Apart + EQ + idx);
  bf16x8 o;
#pragma unroll
  for (int t = 0; t < 8; t++) o[t] = (bf16)(((float)a0[t] + (float)a1[t]) * inv);
  *(bf16x8*)(AO + idx) = o;
}

// ---------------------------------------------------------------------------
extern "C" void kernel_launch(void* const* d_in, const int* in_sizes, int n_in,
                              void* d_out, int out_size, void* d_ws, size_t ws_size,
                              hipStream_t stream) {
  const float* q    = (const float*)d_in[0];
  const float* k    = (const float*)d_in[1];
  const float* v    = (const float*)d_in[2];
  const float* wq_w = (const float*)d_in[3];
  const float* wq_b = (const float*)d_in[4];
  const float* wk_w = (const float*)d_in[5];
  const float* wk_b = (const float*)d_in[6];
  const float* wv_w = (const float*)d_in[7];
  const float* wv_b = (const float*)d_in[8];
  const float* wo_w = (const float*)d_in[9];
  const float* wo_b = (const float*)d_in[10];

  bf16* W = (bf16*)d_ws;
  const size_t NTOK = (size_t)B_ * S_;   // 4096
  const size_t EQ = NTOK * D_;
  const size_t EW = (size_t)D_ * D_;
  bf16* qb  = W;          // later reused: Apart (2 contiguous halves, 16MB)
  bf16* kb  = qb  + EQ;
  bf16* vb  = kb  + EQ;   // later reused: Lpart (fp32, 0.5MB)
  bf16* Qhb = vb  + EQ;   // [B,H,S,64], pre-scaled
  bf16* Khb = Qhb + EQ;   // [B,H,S,64]
  bf16* Vtb = Khb + EQ;   // [H,64,B,S]
  bf16* AOb = Vtb + EQ;   // [B,S,H*64]
  bf16* wqb = AOb + EQ;
  bf16* wkb = wqb + EW;
  bf16* wvb = wkb + EW;
  bf16* wob = wvb + EW;   // 64 MiB total

  bf16*  Apart = qb;           // 2 x EQ bf16 (overwrites dead qb/kb)
  float* Lpart = (float*)vb;   // 2 x B*H*S fp32 (overwrites dead vb)

  cast_all<<<8192, 256, 0, stream>>>(q, k, v, wq_w, wk_w, wv_w, wo_w,
                                     qb, kb, vb, wqb, wkb, wvb, wob);

  gemm_qkv<<<dim3(512, 3), 256, 0, stream>>>(qb, kb, vb, wqb, wkb, wvb,
                                             wq_b, wk_b, wv_b, Qhb, Khb, Vtb);

  flash_attn<<<1024, 256, 0, stream>>>(Qhb, Khb, Vtb, Apart, Lpart);

  combine<<<2048, 256, 0, stream>>>(Apart, Lpart, AOb);

  gemm_out<<<512, 256, 0, stream>>>(AOb, wob, wo_b, (float*)d_out);
}

// Round 3
// 231.509 us; speedup vs baseline: 1.0257x; 1.0257x over previous
//
#include <hip/hip_runtime.h>

// Problem constants
#define B_  2
#define S_  2048
#define D_  1024
#define H_  16
#define DK_ 64

typedef __bf16 bf16;
typedef __bf16 bf16x8 __attribute__((ext_vector_type(8)));
typedef __bf16 bf16x4 __attribute__((ext_vector_type(4)));
typedef float  f32x4  __attribute__((ext_vector_type(4)));

#define GLD16(gptr, lptr) __builtin_amdgcn_global_load_lds( \
    (const __attribute__((address_space(1))) void*)(gptr),  \
    (__attribute__((address_space(3))) void*)(lptr), 16, 0, 0)

// ---------------------------------------------------------------------------
// fused fp32 -> bf16 cast for all 7 tensors in ONE launch (2048 elems/block)
// ---------------------------------------------------------------------------
__global__ __launch_bounds__(256) void cast_all(
    const float* __restrict__ q, const float* __restrict__ k, const float* __restrict__ v,
    const float* __restrict__ wq, const float* __restrict__ wk, const float* __restrict__ wv,
    const float* __restrict__ wo,
    bf16* __restrict__ qb, bf16* __restrict__ kb, bf16* __restrict__ vb,
    bf16* __restrict__ wqb, bf16* __restrict__ wkb, bf16* __restrict__ wvb,
    bf16* __restrict__ wob) {
  int blk = blockIdx.x;
  const float* in; bf16* out; int base;
  if      (blk < 2048) { in = q;  out = qb;  base = blk; }
  else if (blk < 4096) { in = k;  out = kb;  base = blk - 2048; }
  else if (blk < 6144) { in = v;  out = vb;  base = blk - 4096; }
  else if (blk < 6656) { in = wq; out = wqb; base = blk - 6144; }
  else if (blk < 7168) { in = wk; out = wkb; base = blk - 6656; }
  else if (blk < 7680) { in = wv; out = wvb; base = blk - 7168; }
  else                 { in = wo; out = wob; base = blk - 7680; }
  int i = (base * 256 + threadIdx.x) * 8;
  float4 a = *(const float4*)(in + i);
  float4 b = *(const float4*)(in + i + 4);
  bf16x8 o;
  o[0] = (bf16)a.x; o[1] = (bf16)a.y; o[2] = (bf16)a.z; o[3] = (bf16)a.w;
  o[4] = (bf16)b.x; o[5] = (bf16)b.y; o[6] = (bf16)b.z; o[7] = (bf16)b.w;
  *(bf16x8*)(out + i) = o;
}

// ---------------------------------------------------------------------------
// Fused Q/K/V projection — r11: 128x128 tile (m97 ladder rung, 912 TF verified
// vs ~505 TF of the old 128x64: doubled MFMA:staging ratio + 2x B-reuse).
// BK=64, 4 waves in 2x2, acc 4x4/wave, LDS 32KB, 3 blocks/CU -> grid 768 =
// perfect residency at __launch_bounds__(256,3).
// z=0: Qh = (q Wq^T + b)*sc2 (pre-scaled), head-split [B,H,S,64]
// z=1: Kh = k Wk^T + b, head-split;  z=2: Vt = Wv v^T + b(row), [D, B*S]
// ---------------------------------------------------------------------------
__global__ __launch_bounds__(256, 3) void gemm_qkv(
    const bf16* __restrict__ qb, const bf16* __restrict__ kb, const bf16* __restrict__ vb,
    const bf16* __restrict__ wq, const bf16* __restrict__ wk, const bf16* __restrict__ wv,
    const float* __restrict__ biq, const float* __restrict__ bik, const float* __restrict__ biv,
    bf16* __restrict__ Qh, bf16* __restrict__ Kh, bf16* __restrict__ Vt) {
  __shared__ bf16 As[128 * 64];   // 16 KB
  __shared__ bf16 Bs[128 * 64];   // 16 KB
  const int z = blockIdx.y;
  const bf16 *A, *Bm; const float* bias; bf16* Cout;
  int bx, by, N;
  if (z == 0)      { A = qb; Bm = wq; bias = biq; Cout = Qh; }
  else if (z == 1) { A = kb; Bm = wk; bias = bik; Cout = Kh; }
  else             { A = wv; Bm = vb; bias = biv; Cout = Vt; }
  // z<2: M=4096 (32 tiles) x N=1024 (8 tiles); z=2: M=1024 (8) x N=4096 (32)
  if (z < 2) { by = blockIdx.x & 31; bx = blockIdx.x >> 5; N = D_; }
  else       { bx = blockIdx.x & 31; by = blockIdx.x >> 5; N = B_ * S_; }
  const int K = D_;

  const int tid  = threadIdx.x;
  const int wave = tid >> 6, lane = tid & 63;
  const int g = lane >> 4, r = lane & 15;
  const int wr = wave >> 1, wc = wave & 1;      // 2x2 wave grid, 64x64 each
  const int m0 = by * 128, n0 = bx * 128;

  f32x4 acc[4][4] = {};
  const int srow = tid >> 3;  // 0..31
  const int sp   = tid & 7;   // 16B block in 128B row

  for (int k0 = 0; k0 < K; k0 += 64) {
    __syncthreads();
#pragma unroll
    for (int rep = 0; rep < 4; rep++) {       // A: 128 rows
      int row = rep * 32 + srow;
      int bb  = sp ^ (row & 7);
      GLD16(A + (size_t)(m0 + row) * K + k0 + bb * 8, As + rep * 2048 + wave * 512);
    }
#pragma unroll
    for (int rep = 0; rep < 4; rep++) {       // B: 128 rows
      int row = rep * 32 + srow;
      int bb  = sp ^ (row & 7);
      GLD16(Bm + (size_t)(n0 + row) * K + k0 + bb * 8, Bs + rep * 2048 + wave * 512);
    }
    __syncthreads();

#pragma unroll
    for (int kc = 0; kc < 2; kc++) {
      bf16x8 af[4], bfr[4];
#pragma unroll
      for (int i = 0; i < 4; i++) {
        int row = wr * 64 + i * 16 + r;
        af[i] = *(const bf16x8*)(As + row * 64 + (((kc * 4 + g) ^ (row & 7)) * 8));
      }
#pragma unroll
      for (int j = 0; j < 4; j++) {
        int row = wc * 64 + j * 16 + r;
        bfr[j] = *(const bf16x8*)(Bs + row * 64 + (((kc * 4 + g) ^ (row & 7)) * 8));
      }
#pragma unroll
      for (int i = 0; i < 4; i++)
#pragma unroll
        for (int j = 0; j < 4; j++)
          acc[i][j] = __builtin_amdgcn_mfma_f32_16x16x32_bf16(af[i], bfr[j], acc[i][j], 0, 0, 0);
    }
  }

  const float qscale = 0.18033688f;  // (1/sqrt(64)) * log2(e), folded into Q
#pragma unroll
  for (int i = 0; i < 4; i++) {
#pragma unroll
    for (int j = 0; j < 4; j++) {
#pragma unroll
      for (int t = 0; t < 4; t++) {
        int mrow = m0 + wr * 64 + i * 16 + g * 4 + t;
        int col  = n0 + wc * 64 + j * 16 + r;
        float val = acc[i][j][t];
        if (z < 2) {
          val += bias[col];
          if (z == 0) val *= qscale;
          int bb2 = mrow >> 11, s = mrow & (S_ - 1);
          int hh = col >> 6, d = col & 63;
          Cout[(((size_t)(bb2 * H_ + hh)) * S_ + s) * 64 + d] = (bf16)val;
        } else {
          val += bias[mrow];
          Cout[(size_t)mrow * N + col] = (bf16)val;
        }
      }
    }
  }
}

// ---------------------------------------------------------------------------
// Final projection: out = AO Wo^T + b (fp32). r11: 128x128 tile (m97 rung),
// BK=64, 3 blocks/CU. M=4096 (32 tiles) x N=1024 (8 tiles) -> grid 256.
// ---------------------------------------------------------------------------
__global__ __launch_bounds__(256, 3) void gemm_out(const bf16* __restrict__ A,
                                                   const bf16* __restrict__ Bm,
                                                   const float* __restrict__ bias,
                                                   float* __restrict__ Cout) {
  __shared__ bf16 As[128 * 64];   // 16 KB
  __shared__ bf16 Bs[128 * 64];   // 16 KB
  const int K = D_, N = D_;
  const int tid  = threadIdx.x;
  const int wave = tid >> 6, lane = tid & 63;
  const int g = lane >> 4, r = lane & 15;
  const int wr = wave >> 1, wc = wave & 1;
  const int bx = blockIdx.x & 7, by = blockIdx.x >> 3;
  const int m0 = by * 128, n0 = bx * 128;

  f32x4 acc[4][4] = {};
  const int srow = tid >> 3;
  const int sp   = tid & 7;

  for (int k0 = 0; k0 < K; k0 += 64) {
    __syncthreads();
#pragma unroll
    for (int rep = 0; rep < 4; rep++) {
      int row = rep * 32 + srow;
      int bb  = sp ^ (row & 7);
      GLD16(A + (size_t)(m0 + row) * K + k0 + bb * 8, As + rep * 2048 + wave * 512);
    }
#pragma unroll
    for (int rep = 0; rep < 4; rep++) {
      int row = rep * 32 + srow;
      int bb  = sp ^ (row & 7);
      GLD16(Bm + (size_t)(n0 + row) * K + k0 + bb * 8, Bs + rep * 2048 + wave * 512);
    }
    __syncthreads();

#pragma unroll
    for (int kc = 0; kc < 2; kc++) {
      bf16x8 af[4], bfr[4];
#pragma unroll
      for (int i = 0; i < 4; i++) {
        int row = wr * 64 + i * 16 + r;
        af[i] = *(const bf16x8*)(As + row * 64 + (((kc * 4 + g) ^ (row & 7)) * 8));
      }
#pragma unroll
      for (int j = 0; j < 4; j++) {
        int row = wc * 64 + j * 16 + r;
        bfr[j] = *(const bf16x8*)(Bs + row * 64 + (((kc * 4 + g) ^ (row & 7)) * 8));
      }
#pragma unroll
      for (int i = 0; i < 4; i++)
#pragma unroll
        for (int j = 0; j < 4; j++)
          acc[i][j] = __builtin_amdgcn_mfma_f32_16x16x32_bf16(af[i], bfr[j], acc[i][j], 0, 0, 0);
    }
  }

#pragma unroll
  for (int i = 0; i < 4; i++)
#pragma unroll
    for (int j = 0; j < 4; j++)
#pragma unroll
      for (int t = 0; t < 4; t++) {
        int mrow = m0 + wr * 64 + i * 16 + g * 4 + t;
        int col  = n0 + wc * 64 + j * 16 + r;
        Cout[(size_t)mrow * N + col] = acc[i][j][t] + bias[col];
      }
}

// ---------------------------------------------------------------------------
// Flash attention — EXACT R0 revert (50.6us known-good).
// r10 lesson: counted-vmcnt dbuf neutral (stall isn't the staging drain).
// r11 lesson: K=16 PV MFMA is half-rate (same cycles as x32) + its bf16x4
// V-read is 4-way bank-conflicted -> regressed. The Ps LDS round-trip with
// lgkmcnt(0) drains stays until a layout that feeds x32 PV without it exists.
// ---------------------------------------------------------------------------
__global__ __launch_bounds__(256, 4) void flash_attn(const bf16* __restrict__ Qh,
                                                     const bf16* __restrict__ Kh,
                                                     const bf16* __restrict__ Vt,
                                                     bf16* __restrict__ Apart,
                                                     float* __restrict__ Lpart) {
  __shared__ bf16 Ks[64 * 64];    // 8 KB
  __shared__ bf16 Vs[64 * 64];    // 8 KB
  __shared__ bf16 Ps[128 * 40];   // 10 KB, one 32-key chunk, stride 40

  const int tid  = threadIdx.x;
  const int wave = tid >> 6, lane = tid & 63;
  const int g = lane >> 4, r = lane & 15;

  int qt = blockIdx.x >> 6;          // 0..15
  int kh = blockIdx.x & 1;           // 0..1
  int bh = (blockIdx.x >> 1) & 31;   // 0..31
  int h = bh & (H_ - 1), b = bh >> 4;

  const bf16* Kbase = Kh + ((size_t)bh * S_ + kh * 1024) * DK_;
  const bf16* Vbase = Vt + (size_t)h * 64 * (B_ * S_) + (size_t)b * S_ + kh * 1024;

  bf16x8 bq[2][2];
#pragma unroll
  for (int sq = 0; sq < 2; sq++) {
    int qrow = qt * 128 + wave * 32 + sq * 16 + r;
    const bf16* qp = Qh + ((size_t)bh * S_ + qrow) * DK_;
#pragma unroll
    for (int kc = 0; kc < 2; kc++)
      bq[sq][kc] = *(const bf16x8*)(qp + kc * 32 + g * 8);
  }

  f32x4 acc_o[2][4] = {};
  float l_run[2] = {0.f, 0.f};

  const int srow = tid >> 3, spp = tid & 7;

  for (int j0 = 0; j0 < 1024 / 64; j0++) {
    __syncthreads();
#pragma unroll
    for (int rep = 0; rep < 2; rep++) {
      int rr = rep * 32 + srow;
      int bb = spp ^ (rr & 7);
      GLD16(Kbase + (size_t)(j0 * 64 + rr) * 64 + bb * 8, Ks + rep * 2048 + wave * 512);
      GLD16(Vbase + (size_t)rr * (B_ * S_) + j0 * 64 + bb * 8, Vs + rep * 2048 + wave * 512);
    }
    __syncthreads();

    bf16x8 ak[4][2];
#pragma unroll
    for (int ks = 0; ks < 4; ks++) {
      int kr = ks * 16 + r;
#pragma unroll
      for (int kc = 0; kc < 2; kc++)
        ak[ks][kc] = *(const bf16x8*)(Ks + kr * 64 + (((kc * 4 + g) ^ (kr & 7)) * 8));
    }
    f32x4 sacc[2][4] = {};
#pragma unroll
    for (int sq = 0; sq < 2; sq++)
#pragma unroll
      for (int ks = 0; ks < 4; ks++)
#pragma unroll
        for (int kc = 0; kc < 2; kc++)
          sacc[sq][ks] = __builtin_amdgcn_mfma_f32_16x16x32_bf16(ak[ks][kc], bq[sq][kc],
                                                                 sacc[sq][ks], 0, 0, 0);

#pragma unroll
    for (int c = 0; c < 2; c++) {
#pragma unroll
      for (int sq = 0; sq < 2; sq++) {
        int qrow = wave * 32 + sq * 16 + r;
        float rs = 0.f;
#pragma unroll
        for (int k2 = 0; k2 < 2; k2++) {
          int ks = c * 2 + k2;
          bf16x4 pk;
#pragma unroll
          for (int t = 0; t < 4; t++) {
            float pv = __builtin_amdgcn_exp2f(sacc[sq][ks][t]);
            rs += pv;
            pk[t] = (bf16)pv;
          }
          *(bf16x4*)(Ps + qrow * 40 + k2 * 16 + g * 4) = pk;
        }
        l_run[sq] += rs;
      }
      asm volatile("s_waitcnt lgkmcnt(0)" ::: "memory");

      bf16x8 bp[2];
#pragma unroll
      for (int sq = 0; sq < 2; sq++) {
        int qrow = wave * 32 + sq * 16 + r;
        bp[sq] = *(const bf16x8*)(Ps + qrow * 40 + g * 8);
      }
#pragma unroll
      for (int dsub = 0; dsub < 4; dsub++) {
        int dr = dsub * 16 + r;
        bf16x8 av = *(const bf16x8*)(Vs + dr * 64 + (((c * 4 + g) ^ (dr & 7)) * 8));
#pragma unroll
        for (int sq = 0; sq < 2; sq++)
          acc_o[sq][dsub] = __builtin_amdgcn_mfma_f32_16x16x32_bf16(av, bp[sq],
                                                                    acc_o[sq][dsub], 0, 0, 0);
      }
    }
  }

#pragma unroll
  for (int sq = 0; sq < 2; sq++) {
    float l = l_run[sq];
    l += __shfl_xor(l, 16, 64);
    l += __shfl_xor(l, 32, 64);
    int s = qt * 128 + wave * 32 + sq * 16 + r;
    if (g == 0)
      Lpart[(size_t)kh * (B_ * H_ * S_) + (size_t)bh * S_ + s] = l;
    size_t base = (size_t)kh * (B_ * S_ * (size_t)D_) + ((size_t)b * S_ + s) * D_ + (size_t)h * 64;
#pragma unroll
    for (int dsub = 0; dsub < 4; dsub++) {
      bf16x4 o;
#pragma unroll
      for (int t = 0; t < 4; t++) o[t] = (bf16)(acc_o[sq][dsub][t]);
      *(bf16x4*)(Apart + base + dsub * 16 + g * 4) = o;
    }
  }
}

// ---------------------------------------------------------------------------
// combine: AO = (A0 + A1) / (l0 + l1). 8 elems/thread.
// ---------------------------------------------------------------------------
__global__ __launch_bounds__(256) void combine(const bf16* __restrict__ Apart,
                                               const float* __restrict__ Lpart,
                                               bf16* __restrict__ AO) {
  const size_t EQ = (size_t)B_ * S_ * D_;
  const int LHALF = B_ * H_ * S_;
  int idx = (blockIdx.x * 256 + threadIdx.x) * 8;
  int token = idx >> 10;           // b*S + s
  int dcol  = idx & (D_ - 1);
  int b = token >> 11, s = token & (S_ - 1);
  int h = dcol >> 6;
  int li = (b * H_ + h) * S_ + s;
  float inv = 1.0f / (Lpart[li] + Lpart[li + LHALF]);
  bf16x8 a0 = *(const bf16x8*)(Apart + idx);
  bf16x8 a1 = *(const bf16x8*)(Apart + EQ + idx);
  bf16x8 o;
#pragma unroll
  for (int t = 0; t < 8; t++) o[t] = (bf16)(((float)a0[t] + (float)a1[t]) * inv);
  *(bf16x8*)(AO + idx) = o;
}

// ---------------------------------------------------------------------------
extern "C" void kernel_launch(void* const* d_in, const int* in_sizes, int n_in,
                              void* d_out, int out_size, void* d_ws, size_t ws_size,
                              hipStream_t stream) {
  const float* q    = (const float*)d_in[0];
  const float* k    = (const float*)d_in[1];
  const float* v    = (const float*)d_in[2];
  const float* wq_w = (const float*)d_in[3];
  const float* wq_b = (const float*)d_in[4];
  const float* wk_w = (const float*)d_in[5];
  const float* wk_b = (const float*)d_in[6];
  const float* wv_w = (const float*)d_in[7];
  const float* wv_b = (const float*)d_in[8];
  const float* wo_w = (const float*)d_in[9];
  const float* wo_b = (const float*)d_in[10];

  bf16* W = (bf16*)d_ws;
  const size_t NTOK = (size_t)B_ * S_;   // 4096
  const size_t EQ = NTOK * D_;
  const size_t EW = (size_t)D_ * D_;
  bf16* qb  = W;          // later reused: Apart (2 contiguous halves, 16MB)
  bf16* kb  = qb  + EQ;
  bf16* vb  = kb  + EQ;   // later reused: Lpart (fp32, 0.5MB)
  bf16* Qhb = vb  + EQ;   // [B,H,S,64], pre-scaled
  bf16* Khb = Qhb + EQ;   // [B,H,S,64]
  bf16* Vtb = Khb + EQ;   // [H,64,B,S]
  bf16* AOb = Vtb + EQ;   // [B,S,H*64]
  bf16* wqb = AOb + EQ;
  bf16* wkb = wqb + EW;
  bf16* wvb = wkb + EW;
  bf16* wob = wvb + EW;   // 64 MiB total

  bf16*  Apart = qb;           // 2 x EQ bf16 (overwrites dead qb/kb)
  float* Lpart = (float*)vb;   // 2 x B*H*S fp32 (overwrites dead vb)

  cast_all<<<8192, 256, 0, stream>>>(q, k, v, wq_w, wk_w, wv_w, wo_w,
                                     qb, kb, vb, wqb, wkb, wvb, wob);

  gemm_qkv<<<dim3(256, 3), 256, 0, stream>>>(qb, kb, vb, wqb, wkb, wvb,
                                             wq_b, wk_b, wv_b, Qhb, Khb, Vtb);

  flash_attn<<<1024, 256, 0, stream>>>(Qhb, Khb, Vtb, Apart, Lpart);

  combine<<<2048, 256, 0, stream>>>(Apart, Lpart, AOb);

  gemm_out<<<256, 256, 0, stream>>>(AOb, wob, wo_b, (float*)d_out);
}

// Round 4
// 219.403 us; speedup vs baseline: 1.0823x; 1.0552x over previous
//
#include <hip/hip_runtime.h>

// Problem constants
#define B_  2
#define S_  2048
#define D_  1024
#define H_  16
#define DK_ 64

typedef __bf16 bf16;
typedef __bf16 bf16x8 __attribute__((ext_vector_type(8)));
typedef __bf16 bf16x4 __attribute__((ext_vector_type(4)));
typedef float  f32x4  __attribute__((ext_vector_type(4)));

#define GLD16(gptr, lptr) __builtin_amdgcn_global_load_lds( \
    (const __attribute__((address_space(1))) void*)(gptr),  \
    (__attribute__((address_space(3))) void*)(lptr), 16, 0, 0)

// ---------------------------------------------------------------------------
// fused fp32 -> bf16 cast for all 7 tensors in ONE launch (2048 elems/block)
// ---------------------------------------------------------------------------
__global__ __launch_bounds__(256) void cast_all(
    const float* __restrict__ q, const float* __restrict__ k, const float* __restrict__ v,
    const float* __restrict__ wq, const float* __restrict__ wk, const float* __restrict__ wv,
    const float* __restrict__ wo,
    bf16* __restrict__ qb, bf16* __restrict__ kb, bf16* __restrict__ vb,
    bf16* __restrict__ wqb, bf16* __restrict__ wkb, bf16* __restrict__ wvb,
    bf16* __restrict__ wob) {
  int blk = blockIdx.x;
  const float* in; bf16* out; int base;
  if      (blk < 2048) { in = q;  out = qb;  base = blk; }
  else if (blk < 4096) { in = k;  out = kb;  base = blk - 2048; }
  else if (blk < 6144) { in = v;  out = vb;  base = blk - 4096; }
  else if (blk < 6656) { in = wq; out = wqb; base = blk - 6144; }
  else if (blk < 7168) { in = wk; out = wkb; base = blk - 6656; }
  else if (blk < 7680) { in = wv; out = wvb; base = blk - 7168; }
  else                 { in = wo; out = wob; base = blk - 7680; }
  int i = (base * 256 + threadIdx.x) * 8;
  float4 a = *(const float4*)(in + i);
  float4 b = *(const float4*)(in + i + 4);
  bf16x8 o;
  o[0] = (bf16)a.x; o[1] = (bf16)a.y; o[2] = (bf16)a.z; o[3] = (bf16)a.w;
  o[4] = (bf16)b.x; o[5] = (bf16)b.y; o[6] = (bf16)b.z; o[7] = (bf16)b.w;
  *(bf16x8*)(out + i) = o;
}

// ---------------------------------------------------------------------------
// Fused Q/K/V projection — EXACT R0 revert (128x64 tile, BK=64, 6 blocks/CU).
// r12 lesson: 128x128@3/CU regressed (~+10us) at K=1024/N=1024 — B-panels
// are L2-resident so reuse gain is moot, occupancy cost is real.
// z=0: Qh = (q Wq^T + b)*sc2 (pre-scaled), head-split [B,H,S,64]
// z=1: Kh = k Wk^T + b, head-split;  z=2: Vt = Wv v^T + b(row), [D, B*S]
// ---------------------------------------------------------------------------
__global__ __launch_bounds__(256, 6) void gemm_qkv(
    const bf16* __restrict__ qb, const bf16* __restrict__ kb, const bf16* __restrict__ vb,
    const bf16* __restrict__ wq, const bf16* __restrict__ wk, const bf16* __restrict__ wv,
    const float* __restrict__ biq, const float* __restrict__ bik, const float* __restrict__ biv,
    bf16* __restrict__ Qh, bf16* __restrict__ Kh, bf16* __restrict__ Vt) {
  __shared__ bf16 As[128 * 64];   // 16 KB
  __shared__ bf16 Bs[64 * 64];    // 8 KB
  const int z = blockIdx.y;
  const bf16 *A, *Bm; const float* bias; bf16* Cout;
  int bx, by, N;
  if (z == 0)      { A = qb; Bm = wq; bias = biq; Cout = Qh; }
  else if (z == 1) { A = kb; Bm = wk; bias = bik; Cout = Kh; }
  else             { A = wv; Bm = vb; bias = biv; Cout = Vt; }
  if (z < 2) { by = blockIdx.x & 31; bx = blockIdx.x >> 5; N = D_; }
  else       { bx = blockIdx.x & 63; by = blockIdx.x >> 6; N = B_ * S_; }
  const int K = D_;

  const int tid  = threadIdx.x;
  const int wave = tid >> 6, lane = tid & 63;
  const int g = lane >> 4, r = lane & 15;
  const int m0 = by * 128, n0 = bx * 64;

  f32x4 acc[2][4] = {};
  const int srow = tid >> 3;  // 0..31
  const int sp   = tid & 7;   // 16B block in 128B row

  for (int k0 = 0; k0 < K; k0 += 64) {
    __syncthreads();
#pragma unroll
    for (int rep = 0; rep < 4; rep++) {       // A: 128 rows
      int row = rep * 32 + srow;
      int bb  = sp ^ (row & 7);
      GLD16(A + (size_t)(m0 + row) * K + k0 + bb * 8, As + rep * 2048 + wave * 512);
    }
#pragma unroll
    for (int rep = 0; rep < 2; rep++) {       // B: 64 rows
      int row = rep * 32 + srow;
      int bb  = sp ^ (row & 7);
      GLD16(Bm + (size_t)(n0 + row) * K + k0 + bb * 8, Bs + rep * 2048 + wave * 512);
    }
    __syncthreads();

#pragma unroll
    for (int kc = 0; kc < 2; kc++) {
      bf16x8 af[2], bfr[4];
#pragma unroll
      for (int i = 0; i < 2; i++) {
        int row = wave * 32 + i * 16 + r;
        af[i] = *(const bf16x8*)(As + row * 64 + (((kc * 4 + g) ^ (row & 7)) * 8));
      }
#pragma unroll
      for (int j = 0; j < 4; j++) {
        int row = j * 16 + r;
        bfr[j] = *(const bf16x8*)(Bs + row * 64 + (((kc * 4 + g) ^ (row & 7)) * 8));
      }
#pragma unroll
      for (int i = 0; i < 2; i++)
#pragma unroll
        for (int j = 0; j < 4; j++)
          acc[i][j] = __builtin_amdgcn_mfma_f32_16x16x32_bf16(af[i], bfr[j], acc[i][j], 0, 0, 0);
    }
  }

  const float qscale = 0.18033688f;  // (1/sqrt(64)) * log2(e), folded into Q
#pragma unroll
  for (int i = 0; i < 2; i++) {
#pragma unroll
    for (int j = 0; j < 4; j++) {
#pragma unroll
      for (int t = 0; t < 4; t++) {
        int mrow = m0 + wave * 32 + i * 16 + g * 4 + t;
        int col  = n0 + j * 16 + r;
        float val = acc[i][j][t];
        if (z < 2) {
          val += bias[col];
          if (z == 0) val *= qscale;
          int bb2 = mrow >> 11, s = mrow & (S_ - 1);
          int hh = col >> 6, d = col & 63;
          Cout[(((size_t)(bb2 * H_ + hh)) * S_ + s) * 64 + d] = (bf16)val;
        } else {
          val += bias[mrow];
          Cout[(size_t)mrow * N + col] = (bf16)val;
        }
      }
    }
  }
}

// ---------------------------------------------------------------------------
// Final projection — EXACT R0 revert (128x64 tile, BK=64, 6 blocks/CU).
// ---------------------------------------------------------------------------
__global__ __launch_bounds__(256, 6) void gemm_out(const bf16* __restrict__ A,
                                                   const bf16* __restrict__ Bm,
                                                   const float* __restrict__ bias,
                                                   float* __restrict__ Cout) {
  __shared__ bf16 As[128 * 64];   // 16 KB
  __shared__ bf16 Bs[64 * 64];    // 8 KB
  const int K = D_, N = D_;
  const int tid  = threadIdx.x;
  const int wave = tid >> 6, lane = tid & 63;
  const int g = lane >> 4, r = lane & 15;
  const int bx = blockIdx.x & 15, by = blockIdx.x >> 4;
  const int m0 = by * 128, n0 = bx * 64;

  f32x4 acc[2][4] = {};
  const int srow = tid >> 3;
  const int sp   = tid & 7;

  for (int k0 = 0; k0 < K; k0 += 64) {
    __syncthreads();
#pragma unroll
    for (int rep = 0; rep < 4; rep++) {
      int row = rep * 32 + srow;
      int bb  = sp ^ (row & 7);
      GLD16(A + (size_t)(m0 + row) * K + k0 + bb * 8, As + rep * 2048 + wave * 512);
    }
#pragma unroll
    for (int rep = 0; rep < 2; rep++) {
      int row = rep * 32 + srow;
      int bb  = sp ^ (row & 7);
      GLD16(Bm + (size_t)(n0 + row) * K + k0 + bb * 8, Bs + rep * 2048 + wave * 512);
    }
    __syncthreads();

#pragma unroll
    for (int kc = 0; kc < 2; kc++) {
      bf16x8 af[2], bfr[4];
#pragma unroll
      for (int i = 0; i < 2; i++) {
        int row = wave * 32 + i * 16 + r;
        af[i] = *(const bf16x8*)(As + row * 64 + (((kc * 4 + g) ^ (row & 7)) * 8));
      }
#pragma unroll
      for (int j = 0; j < 4; j++) {
        int row = j * 16 + r;
        bfr[j] = *(const bf16x8*)(Bs + row * 64 + (((kc * 4 + g) ^ (row & 7)) * 8));
      }
#pragma unroll
      for (int i = 0; i < 2; i++)
#pragma unroll
        for (int j = 0; j < 4; j++)
          acc[i][j] = __builtin_amdgcn_mfma_f32_16x16x32_bf16(af[i], bfr[j], acc[i][j], 0, 0, 0);
    }
  }

#pragma unroll
  for (int i = 0; i < 2; i++)
#pragma unroll
    for (int j = 0; j < 4; j++)
#pragma unroll
      for (int t = 0; t < 4; t++) {
        int mrow = m0 + wave * 32 + i * 16 + g * 4 + t;
        int col  = n0 + j * 16 + r;
        Cout[(size_t)mrow * N + col] = acc[i][j][t] + bias[col];
      }
}

// ---------------------------------------------------------------------------
// Flash attention v4 — wider per-wave q-tile (sq 2->4: 64 q-rows/wave, 256
// rows/block). Mechanism: ak/av LDS reads per wave-iter UNCHANGED (16KB)
// while MFMAs double to 64 -> LDS-traffic-per-MFMA halves; 32 independent
// MFMAs per phase give deep ILP so 2 blocks/CU suffices. grid 512 = clean
// 2/CU residency. K/V re-read count halves (8 qt blocks vs 16) -> FETCH ~1/2.
// Inner mechanics byte-identical to proven R0 (staging, Ps stride-40
// round-trip, lgkm drain, epilogue) — only loop bounds/indexing changed.
// ---------------------------------------------------------------------------
__global__ __launch_bounds__(256, 2) void flash_attn(const bf16* __restrict__ Qh,
                                                     const bf16* __restrict__ Kh,
                                                     const bf16* __restrict__ Vt,
                                                     bf16* __restrict__ Apart,
                                                     float* __restrict__ Lpart) {
  __shared__ bf16 Ks[64 * 64];    // 8 KB
  __shared__ bf16 Vs[64 * 64];    // 8 KB
  __shared__ bf16 Ps[256 * 40];   // 20 KB, one 32-key chunk, stride 40

  const int tid  = threadIdx.x;
  const int wave = tid >> 6, lane = tid & 63;
  const int g = lane >> 4, r = lane & 15;

  int qt = blockIdx.x >> 6;          // 0..7 (256-row q-tiles)
  int kh = blockIdx.x & 1;           // 0..1
  int bh = (blockIdx.x >> 1) & 31;   // 0..31
  int h = bh & (H_ - 1), b = bh >> 4;

  const bf16* Kbase = Kh + ((size_t)bh * S_ + kh * 1024) * DK_;
  const bf16* Vbase = Vt + (size_t)h * 64 * (B_ * S_) + (size_t)b * S_ + kh * 1024;

  bf16x8 bq[4][2];
#pragma unroll
  for (int sq = 0; sq < 4; sq++) {
    int qrow = qt * 256 + wave * 64 + sq * 16 + r;
    const bf16* qp = Qh + ((size_t)bh * S_ + qrow) * DK_;
#pragma unroll
    for (int kc = 0; kc < 2; kc++)
      bq[sq][kc] = *(const bf16x8*)(qp + kc * 32 + g * 8);
  }

  f32x4 acc_o[4][4] = {};
  float l_run[4] = {0.f, 0.f, 0.f, 0.f};

  const int srow = tid >> 3, spp = tid & 7;

  for (int j0 = 0; j0 < 1024 / 64; j0++) {
    __syncthreads();
#pragma unroll
    for (int rep = 0; rep < 2; rep++) {
      int rr = rep * 32 + srow;
      int bb = spp ^ (rr & 7);
      GLD16(Kbase + (size_t)(j0 * 64 + rr) * 64 + bb * 8, Ks + rep * 2048 + wave * 512);
      GLD16(Vbase + (size_t)rr * (B_ * S_) + j0 * 64 + bb * 8, Vs + rep * 2048 + wave * 512);
    }
    __syncthreads();

    bf16x8 ak[4][2];
#pragma unroll
    for (int ks = 0; ks < 4; ks++) {
      int kr = ks * 16 + r;
#pragma unroll
      for (int kc = 0; kc < 2; kc++)
        ak[ks][kc] = *(const bf16x8*)(Ks + kr * 64 + (((kc * 4 + g) ^ (kr & 7)) * 8));
    }
    f32x4 sacc[4][4] = {};
#pragma unroll
    for (int sq = 0; sq < 4; sq++)
#pragma unroll
      for (int ks = 0; ks < 4; ks++)
#pragma unroll
        for (int kc = 0; kc < 2; kc++)
          sacc[sq][ks] = __builtin_amdgcn_mfma_f32_16x16x32_bf16(ak[ks][kc], bq[sq][kc],
                                                                 sacc[sq][ks], 0, 0, 0);

#pragma unroll
    for (int c = 0; c < 2; c++) {
#pragma unroll
      for (int sq = 0; sq < 4; sq++) {
        int qrow = wave * 64 + sq * 16 + r;
        float rs = 0.f;
#pragma unroll
        for (int k2 = 0; k2 < 2; k2++) {
          int ks = c * 2 + k2;
          bf16x4 pk;
#pragma unroll
          for (int t = 0; t < 4; t++) {
            float pv = __builtin_amdgcn_exp2f(sacc[sq][ks][t]);
            rs += pv;
            pk[t] = (bf16)pv;
          }
          *(bf16x4*)(Ps + qrow * 40 + k2 * 16 + g * 4) = pk;
        }
        l_run[sq] += rs;
      }
      asm volatile("s_waitcnt lgkmcnt(0)" ::: "memory");

      bf16x8 bp[4];
#pragma unroll
      for (int sq = 0; sq < 4; sq++) {
        int qrow = wave * 64 + sq * 16 + r;
        bp[sq] = *(const bf16x8*)(Ps + qrow * 40 + g * 8);
      }
#pragma unroll
      for (int dsub = 0; dsub < 4; dsub++) {
        int dr = dsub * 16 + r;
        bf16x8 av = *(const bf16x8*)(Vs + dr * 64 + (((c * 4 + g) ^ (dr & 7)) * 8));
#pragma unroll
        for (int sq = 0; sq < 4; sq++)
          acc_o[sq][dsub] = __builtin_amdgcn_mfma_f32_16x16x32_bf16(av, bp[sq],
                                                                    acc_o[sq][dsub], 0, 0, 0);
      }
    }
  }

#pragma unroll
  for (int sq = 0; sq < 4; sq++) {
    float l = l_run[sq];
    l += __shfl_xor(l, 16, 64);
    l += __shfl_xor(l, 32, 64);
    int s = qt * 256 + wave * 64 + sq * 16 + r;
    if (g == 0)
      Lpart[(size_t)kh * (B_ * H_ * S_) + (size_t)bh * S_ + s] = l;
    size_t base = (size_t)kh * (B_ * S_ * (size_t)D_) + ((size_t)b * S_ + s) * D_ + (size_t)h * 64;
#pragma unroll
    for (int dsub = 0; dsub < 4; dsub++) {
      bf16x4 o;
#pragma unroll
      for (int t = 0; t < 4; t++) o[t] = (bf16)(acc_o[sq][dsub][t]);
      *(bf16x4*)(Apart + base + dsub * 16 + g * 4) = o;
    }
  }
}

// ---------------------------------------------------------------------------
// combine: AO = (A0 + A1) / (l0 + l1). 8 elems/thread.
// ---------------------------------------------------------------------------
__global__ __launch_bounds__(256) void combine(const bf16* __restrict__ Apart,
                                               const float* __restrict__ Lpart,
                                               bf16* __restrict__ AO) {
  const size_t EQ = (size_t)B_ * S_ * D_;
  const int LHALF = B_ * H_ * S_;
  int idx = (blockIdx.x * 256 + threadIdx.x) * 8;
  int token = idx >> 10;           // b*S + s
  int dcol  = idx & (D_ - 1);
  int b = token >> 11, s = token & (S_ - 1);
  int h = dcol >> 6;
  int li = (b * H_ + h) * S_ + s;
  float inv = 1.0f / (Lpart[li] + Lpart[li + LHALF]);
  bf16x8 a0 = *(const bf16x8*)(Apart + idx);
  bf16x8 a1 = *(const bf16x8*)(Apart + EQ + idx);
  bf16x8 o;
#pragma unroll
  for (int t = 0; t < 8; t++) o[t] = (bf16)(((float)a0[t] + (float)a1[t]) * inv);
  *(bf16x8*)(AO + idx) = o;
}

// ---------------------------------------------------------------------------
extern "C" void kernel_launch(void* const* d_in, const int* in_sizes, int n_in,
                              void* d_out, int out_size, void* d_ws, size_t ws_size,
                              hipStream_t stream) {
  const float* q    = (const float*)d_in[0];
  const float* k    = (const float*)d_in[1];
  const float* v    = (const float*)d_in[2];
  const float* wq_w = (const float*)d_in[3];
  const float* wq_b = (const float*)d_in[4];
  const float* wk_w = (const float*)d_in[5];
  const float* wk_b = (const float*)d_in[6];
  const float* wv_w = (const float*)d_in[7];
  const float* wv_b = (const float*)d_in[8];
  const float* wo_w = (const float*)d_in[9];
  const float* wo_b = (const float*)d_in[10];

  bf16* W = (bf16*)d_ws;
  const size_t NTOK = (size_t)B_ * S_;   // 4096
  const size_t EQ = NTOK * D_;
  const size_t EW = (size_t)D_ * D_;
  bf16* qb  = W;          // later reused: Apart (2 contiguous halves, 16MB)
  bf16* kb  = qb  + EQ;
  bf16* vb  = kb  + EQ;   // later reused: Lpart (fp32, 0.5MB)
  bf16* Qhb = vb  + EQ;   // [B,H,S,64], pre-scaled
  bf16* Khb = Qhb + EQ;   // [B,H,S,64]
  bf16* Vtb = Khb + EQ;   // [H,64,B,S]
  bf16* AOb = Vtb + EQ;   // [B,S,H*64]
  bf16* wqb = AOb + EQ;
  bf16* wkb = wqb + EW;
  bf16* wvb = wkb + EW;
  bf16* wob = wvb + EW;   // 64 MiB total

  bf16*  Apart = qb;           // 2 x EQ bf16 (overwrites dead qb/kb)
  float* Lpart = (float*)vb;   // 2 x B*H*S fp32 (overwrites dead vb)

  cast_all<<<8192, 256, 0, stream>>>(q, k, v, wq_w, wk_w, wv_w, wo_w,
                                     qb, kb, vb, wqb, wkb, wvb, wob);

  gemm_qkv<<<dim3(512, 3), 256, 0, stream>>>(qb, kb, vb, wqb, wkb, wvb,
                                             wq_b, wk_b, wv_b, Qhb, Khb, Vtb);

  flash_attn<<<512, 256, 0, stream>>>(Qhb, Khb, Vtb, Apart, Lpart);

  combine<<<2048, 256, 0, stream>>>(Apart, Lpart, AOb);

  gemm_out<<<512, 256, 0, stream>>>(AOb, wob, wo_b, (float*)d_out);
}